// Round 2
// baseline (1605.387 us; speedup 1.0000x reference)
//
#include <hip/hip_runtime.h>

// Symmetric contraction (MACE-style), N=1024 nodes, C=128 ch, D=9, S=10 species, corr=3.
//   out[n,c,i] = sum_{monomials m of deg<=3 in x[n,c,:]} Uw[index[n], m, i, c] * mono_m(x[n,c,:])
// Kernel 1 (precompute_uw): fold u-tensors (symmetrized over permutations) with per-species
//   weights -> Uw[s][mono][c][9] split as uwA (8 floats) + uwB (1 float). 10.1 MB, L2/L3-resident.
// Kernel 2 (build_groups): counting-sort nodes by species; blockmap of (species, chunk).
// Kernel 3 (symcon_main): block = 4 nodes of ONE species; thread = (c, 2 nodes).
//   One coefficient load feeds 2 nodes (18 FMAs) -> coefficient traffic ~270 MB vs 1.03 GB naive.

#define NMONO3 165
#define NMONO2 45
#define NMONO  219   // 165 + 45 + 9
#define NN 1024
#define NC 128
#define NS 10
#define NPB 4                       // nodes per block (same species)
#define MAXBLK (NN / NPB + NS)      // 266: worst-case sum of per-species ceil chunks

__device__ __forceinline__ void decode3(int m, int& A, int& B, int& J) {
    int cnt = 0;
    for (int a = 0; a < 9; a++)
        for (int b = a; b < 9; b++)
            for (int j = b; j < 9; j++) {
                if (cnt == m) { A = a; B = b; J = j; return; }
                cnt++;
            }
}
__device__ __forceinline__ void decode2(int m, int& A, int& B) {
    int cnt = 0;
    for (int a = 0; a < 9; a++)
        for (int b = a; b < 9; b++) {
            if (cnt == m) { A = a; B = b; return; }
            cnt++;
        }
}

__global__ __launch_bounds__(128) void precompute_uw(
    const float* __restrict__ u1_0e, const float* __restrict__ w1_0e,
    const float* __restrict__ u1_1o, const float* __restrict__ w1_1o,
    const float* __restrict__ u1_2e, const float* __restrict__ w1_2e,
    const float* __restrict__ u2_0e, const float* __restrict__ w2_0e,
    const float* __restrict__ u2_1o, const float* __restrict__ w2_1o,
    const float* __restrict__ u2_2e, const float* __restrict__ w2_2e,
    const float* __restrict__ u3_0e, const float* __restrict__ w3_0e,
    const float* __restrict__ u3_1o, const float* __restrict__ w3_1o,
    const float* __restrict__ u3_2e, const float* __restrict__ w3_2e,
    float* __restrict__ uwA, float* __restrict__ uwB)
{
    const int blk  = blockIdx.x;
    const int s    = blk / NMONO;
    const int mono = blk % NMONO;
    const int c    = threadIdx.x;   // 128 channels
    const int t    = threadIdx.x;
    __shared__ float usum[64];

    // Stage 1: symmetrized u sums (independent of s and c; cheap redundancy across s-blocks).
    if (mono < NMONO3) {
        if (t < 62) {
            int A, B, J; decode3(mono, A, B, J);
            const float* u; int mul, idim, k, i;
            if (t < 4)       { u = u3_0e; mul = 4; idim = 1; k = t; i = 0; }
            else if (t < 22) { u = u3_1o; mul = 6; idim = 3; int r = t - 4;  k = r / 3; i = r % 3; }
            else             { u = u3_2e; mul = 8; idim = 5; int r = t - 22; k = r / 5; i = r % 5; }
            int arr[6] = { A*81+B*9+J, A*81+J*9+B, B*81+A*9+J, B*81+J*9+A, J*81+A*9+B, J*81+B*9+A };
            float sv = 0.f;
            for (int p = 0; p < 6; p++) {
                bool dup = false;
                for (int q = 0; q < p; q++) if (arr[q] == arr[p]) dup = true;
                if (!dup) sv += u[arr[p]*(mul*idim) + k*idim + i];
            }
            usum[t] = sv;
        }
    } else if (mono < NMONO3 + NMONO2) {
        if (t < 23) {
            int A, B; decode2(mono - NMONO3, A, B);
            const float* u; int mul, idim, k, i;
            if (t < 2)      { u = u2_0e; mul = 2; idim = 1; k = t; i = 0; }
            else if (t < 8) { u = u2_1o; mul = 2; idim = 3; int r = t - 2; k = r / 3; i = r % 3; }
            else            { u = u2_2e; mul = 3; idim = 5; int r = t - 8; k = r / 5; i = r % 5; }
            float sv = u[(A*9+B)*(mul*idim) + k*idim + i];
            if (A != B) sv += u[(B*9+A)*(mul*idim) + k*idim + i];
            usum[t] = sv;
        }
    } else {
        if (t < 9) {
            int A = mono - (NMONO3 + NMONO2);
            float sv;
            if (t == 0)      sv = u1_0e[A];
            else if (t < 4)  sv = u1_1o[A*3 + (t-1)];
            else             sv = u1_2e[A*5 + (t-4)];
            usum[t] = sv;
        }
    }
    __syncthreads();

    // Stage 2: contract with per-species weights -> 9 outputs per (s, mono, c).
    float o[9];
    if (mono < NMONO3) {
        float v = 0.f;
        #pragma unroll
        for (int k = 0; k < 4; k++) v += usum[k] * w3_0e[(s*4+k)*NC + c];
        o[0] = v;
        #pragma unroll
        for (int i = 0; i < 3; i++) {
            v = 0.f;
            #pragma unroll
            for (int k = 0; k < 6; k++) v += usum[4 + k*3 + i] * w3_1o[(s*6+k)*NC + c];
            o[1+i] = v;
        }
        #pragma unroll
        for (int i = 0; i < 5; i++) {
            v = 0.f;
            #pragma unroll
            for (int k = 0; k < 8; k++) v += usum[22 + k*5 + i] * w3_2e[(s*8+k)*NC + c];
            o[4+i] = v;
        }
    } else if (mono < NMONO3 + NMONO2) {
        float v = 0.f;
        #pragma unroll
        for (int k = 0; k < 2; k++) v += usum[k] * w2_0e[(s*2+k)*NC + c];
        o[0] = v;
        #pragma unroll
        for (int i = 0; i < 3; i++) {
            v = 0.f;
            #pragma unroll
            for (int k = 0; k < 2; k++) v += usum[2 + k*3 + i] * w2_1o[(s*2+k)*NC + c];
            o[1+i] = v;
        }
        #pragma unroll
        for (int i = 0; i < 5; i++) {
            v = 0.f;
            #pragma unroll
            for (int k = 0; k < 3; k++) v += usum[8 + k*5 + i] * w2_2e[(s*3+k)*NC + c];
            o[4+i] = v;
        }
    } else {
        o[0] = usum[0] * w1_0e[s*NC + c];
        #pragma unroll
        for (int i = 0; i < 3; i++) o[1+i] = usum[1+i] * w1_1o[s*NC + c];
        #pragma unroll
        for (int i = 0; i < 5; i++) o[4+i] = usum[4+i] * w1_2e[s*NC + c];
    }

    const size_t base = (size_t)(s*NMONO + mono)*NC + c;
    #pragma unroll
    for (int q = 0; q < 8; q++) uwA[base*8 + q] = o[q];
    uwB[base] = o[8];
}

// Counting sort of nodes by species + block assignment table. One block, 1024 threads.
__global__ __launch_bounds__(1024) void build_groups(
    const int* __restrict__ index,
    int* __restrict__ perm,      // [NN]
    int* __restrict__ offs,      // [NS+1]
    int* __restrict__ blockmap)  // [MAXBLK*2]: (species, chunk) or (-1, 0)
{
    __shared__ int cnt[NS], pos[NS];
    const int t = threadIdx.x;
    if (t < NS) cnt[t] = 0;
    __syncthreads();
    const int s = index[t];
    atomicAdd(&cnt[s], 1);
    __syncthreads();
    if (t == 0) {
        int o = 0;
        for (int i = 0; i < NS; i++) { offs[i] = o; pos[i] = o; o += cnt[i]; }
        offs[NS] = o;
        int b = 0;
        for (int i = 0; i < NS; i++) {
            int nb = (cnt[i] + NPB - 1) / NPB;
            for (int j = 0; j < nb; j++) { blockmap[2*b] = i; blockmap[2*b+1] = j; b++; }
        }
        for (; b < MAXBLK; b++) { blockmap[2*b] = -1; blockmap[2*b+1] = 0; }
    }
    __syncthreads();
    const int r = atomicAdd(&pos[s], 1);
    perm[r] = t;
}

// Per-monomial: 2x dwordx4 + 1x dword coefficient loads shared by 2 nodes -> 18 FMAs.
#define MONO_BODY(P0E, P1E)                                                 \
    {                                                                       \
        const float4 f0 = *(const float4*)(Abase + (size_t)mono*(NC*8));    \
        const float4 f1 = *(const float4*)(Abase + (size_t)mono*(NC*8)+4);  \
        const float  fb = Bbase[(size_t)mono*NC];                           \
        const float P0 = (P0E), P1 = (P1E);                                 \
        acc[0][0]+=f0.x*P0; acc[0][1]+=f0.y*P0; acc[0][2]+=f0.z*P0;         \
        acc[0][3]+=f0.w*P0; acc[0][4]+=f1.x*P0; acc[0][5]+=f1.y*P0;         \
        acc[0][6]+=f1.z*P0; acc[0][7]+=f1.w*P0; acc[0][8]+=fb  *P0;         \
        acc[1][0]+=f0.x*P1; acc[1][1]+=f0.y*P1; acc[1][2]+=f0.z*P1;         \
        acc[1][3]+=f0.w*P1; acc[1][4]+=f1.x*P1; acc[1][5]+=f1.y*P1;         \
        acc[1][6]+=f1.z*P1; acc[1][7]+=f1.w*P1; acc[1][8]+=fb  *P1;         \
        mono++;                                                             \
    }

__global__ __launch_bounds__(256) void symcon_main(
    const float* __restrict__ x,
    const int* __restrict__ perm, const int* __restrict__ offs,
    const int* __restrict__ blockmap,
    const float* __restrict__ uwA, const float* __restrict__ uwB,
    float* __restrict__ out)
{
    const int s     = blockmap[2*blockIdx.x];
    const int chunk = blockmap[2*blockIdx.x + 1];
    if (s < 0) return;
    const int gbeg = offs[s], gend = offs[s+1];
    const int nstart = gbeg + chunk*NPB;

    const int c = threadIdx.x & 127;
    const int h = threadIdx.x >> 7;   // 0/1: this thread owns nodes h*2, h*2+1 of the chunk

    int  node[2]; bool valid[2];
    float xv[2][9];
    #pragma unroll
    for (int q = 0; q < 2; q++) {
        const int pidx = nstart + h*2 + q;
        valid[q] = (pidx < gend);
        node[q]  = perm[valid[q] ? pidx : gbeg];
        const float* xp = x + ((size_t)node[q]*NC + c)*9;
        #pragma unroll
        for (int d = 0; d < 9; d++) xv[q][d] = xp[d];
    }

    float acc[2][9];
    #pragma unroll
    for (int q = 0; q < 2; q++)
        #pragma unroll
        for (int i = 0; i < 9; i++) acc[q][i] = 0.f;

    const float* Abase = uwA + ((size_t)s*NMONO*NC + c) * 8;
    const float* Bbase = uwB +  (size_t)s*NMONO*NC + c;

    int mono = 0;
    // order 3: x_a x_b x_j, a<=b<=j  (mono 0..164)
    #pragma unroll
    for (int a = 0; a < 9; a++) {
        #pragma unroll
        for (int b = a; b < 9; b++) {
            const float p20 = xv[0][a]*xv[0][b];
            const float p21 = xv[1][a]*xv[1][b];
            #pragma unroll
            for (int j = b; j < 9; j++) {
                MONO_BODY(p20*xv[0][j], p21*xv[1][j])
            }
        }
    }
    // order 2: x_a x_b, a<=b  (mono 165..209)
    #pragma unroll
    for (int a = 0; a < 9; a++) {
        #pragma unroll
        for (int b = a; b < 9; b++) {
            MONO_BODY(xv[0][a]*xv[0][b], xv[1][a]*xv[1][b])
        }
    }
    // order 1: x_a  (mono 210..218)
    #pragma unroll
    for (int a = 0; a < 9; a++) {
        MONO_BODY(xv[0][a], xv[1][a])
    }

    // output row: [0e: c][1o: 128 + c*3+i][2e: 512 + c*5+i], row stride 1152
    #pragma unroll
    for (int q = 0; q < 2; q++) {
        if (!valid[q]) continue;
        float* orow = out + (size_t)node[q] * 1152;
        orow[c] = acc[q][0];
        #pragma unroll
        for (int i = 0; i < 3; i++) orow[128 + c*3 + i] = acc[q][1+i];
        #pragma unroll
        for (int i = 0; i < 5; i++) orow[512 + c*5 + i] = acc[q][4+i];
    }
}

extern "C" void kernel_launch(void* const* d_in, const int* in_sizes, int n_in,
                              void* d_out, int out_size, void* d_ws, size_t ws_size,
                              hipStream_t stream)
{
    // setup_inputs() dict order: x, then (u,w) interleaved for order 1..3 x {0e,1o,2e}, then index.
    const float* x     = (const float*)d_in[0];
    const float* u1_0e = (const float*)d_in[1];
    const float* w1_0e = (const float*)d_in[2];
    const float* u1_1o = (const float*)d_in[3];
    const float* w1_1o = (const float*)d_in[4];
    const float* u1_2e = (const float*)d_in[5];
    const float* w1_2e = (const float*)d_in[6];
    const float* u2_0e = (const float*)d_in[7];
    const float* w2_0e = (const float*)d_in[8];
    const float* u2_1o = (const float*)d_in[9];
    const float* w2_1o = (const float*)d_in[10];
    const float* u2_2e = (const float*)d_in[11];
    const float* w2_2e = (const float*)d_in[12];
    const float* u3_0e = (const float*)d_in[13];
    const float* w3_0e = (const float*)d_in[14];
    const float* u3_1o = (const float*)d_in[15];
    const float* w3_1o = (const float*)d_in[16];
    const float* u3_2e = (const float*)d_in[17];
    const float* w3_2e = (const float*)d_in[18];
    const int*   index = (const int*)d_in[19];
    float* out = (float*)d_out;

    float* uwA = (float*)d_ws;                          // [S][219][128][8] floats
    float* uwB = uwA + (size_t)NS*NMONO*NC*8;           // [S][219][128]    floats
    int*   perm     = (int*)(uwB + (size_t)NS*NMONO*NC);// [NN]
    int*   offs     = perm + NN;                        // [NS+1]
    int*   blockmap = offs + (NS+1);                    // [MAXBLK*2]
    // total ws use ~= 10.1 MB + ~6 KB

    hipLaunchKernelGGL(build_groups, dim3(1), dim3(NN), 0, stream,
        index, perm, offs, blockmap);

    hipLaunchKernelGGL(precompute_uw, dim3(NS*NMONO), dim3(128), 0, stream,
        u1_0e, w1_0e, u1_1o, w1_1o, u1_2e, w1_2e,
        u2_0e, w2_0e, u2_1o, w2_1o, u2_2e, w2_2e,
        u3_0e, w3_0e, u3_1o, w3_1o, u3_2e, w3_2e, uwA, uwB);

    hipLaunchKernelGGL(symcon_main, dim3(MAXBLK), dim3(256), 0, stream,
        x, perm, offs, blockmap, uwA, uwB, out);
}

// Round 4
// 168.645 us; speedup vs baseline: 9.5193x; 9.5193x over previous
//
#include <hip/hip_runtime.h>

// Symmetric contraction (MACE-style), N=1024 nodes, C=128 ch, D=9, S=10 species, corr=3.
//   out[n,c,i] = sum_{monomials m, deg<=3 in x[n,c,:]} Uw[index[n], m, i, c] * mono_m(x[n,c,:])
// Kernel 1 (precompute_uw): fold u-tensors (symmetrized) with per-species weights ->
//   Uw[s][mono][c][9] split as uwA (8 floats) + uwB (1 float). 10.1 MB, L2/L3-resident.
// Kernel 2 (build_groups): counting-sort nodes by species; blockmap of (species, chunk).
// Kernel 3 (symcon_main): RUNTIME loop over 219 monomials (round-2's static 219-deep unroll
//   spilled: VGPR=256, 1.5 GB scratch traffic, 1511 us). x in LDS with runtime (a,b,j) decode
//   from a broadcast LDS table; sentinel lx[*][9]=1.0 makes deg-1/2/3 share one body.
//   Block = 2 nodes (one species) x 128 channels, 1 node/thread.

#define NMONO3 165
#define NMONO2 45
#define NMONO  219   // 165 + 45 + 9
#define NN 1024
#define NC 128
#define NS 10
#define NPB 2                       // nodes per block (same species)
#define MAXBLK (NN / NPB + NS)      // 522: worst-case sum of per-species ceil chunks

__device__ __forceinline__ void decode3(int m, int& A, int& B, int& J) {
    int cnt = 0;
    for (int a = 0; a < 9; a++)
        for (int b = a; b < 9; b++)
            for (int j = b; j < 9; j++) {
                if (cnt == m) { A = a; B = b; J = j; return; }
                cnt++;
            }
}
__device__ __forceinline__ void decode2(int m, int& A, int& B) {
    int cnt = 0;
    for (int a = 0; a < 9; a++)
        for (int b = a; b < 9; b++) {
            if (cnt == m) { A = a; B = b; return; }
            cnt++;
        }
}

__global__ __launch_bounds__(128) void precompute_uw(
    const float* __restrict__ u1_0e, const float* __restrict__ w1_0e,
    const float* __restrict__ u1_1o, const float* __restrict__ w1_1o,
    const float* __restrict__ u1_2e, const float* __restrict__ w1_2e,
    const float* __restrict__ u2_0e, const float* __restrict__ w2_0e,
    const float* __restrict__ u2_1o, const float* __restrict__ w2_1o,
    const float* __restrict__ u2_2e, const float* __restrict__ w2_2e,
    const float* __restrict__ u3_0e, const float* __restrict__ w3_0e,
    const float* __restrict__ u3_1o, const float* __restrict__ w3_1o,
    const float* __restrict__ u3_2e, const float* __restrict__ w3_2e,
    float* __restrict__ uwA, float* __restrict__ uwB)
{
    const int blk  = blockIdx.x;
    const int s    = blk / NMONO;
    const int mono = blk % NMONO;
    const int c    = threadIdx.x;   // 128 channels
    const int t    = threadIdx.x;
    __shared__ float usum[64];

    // Stage 1: symmetrized u sums (independent of s and c; cheap redundancy across s-blocks).
    if (mono < NMONO3) {
        if (t < 62) {
            int A, B, J; decode3(mono, A, B, J);
            const float* u; int mul, idim, k, i;
            if (t < 4)       { u = u3_0e; mul = 4; idim = 1; k = t; i = 0; }
            else if (t < 22) { u = u3_1o; mul = 6; idim = 3; int r = t - 4;  k = r / 3; i = r % 3; }
            else             { u = u3_2e; mul = 8; idim = 5; int r = t - 22; k = r / 5; i = r % 5; }
            int arr[6] = { A*81+B*9+J, A*81+J*9+B, B*81+A*9+J, B*81+J*9+A, J*81+A*9+B, J*81+B*9+A };
            float sv = 0.f;
            for (int p = 0; p < 6; p++) {
                bool dup = false;
                for (int q = 0; q < p; q++) if (arr[q] == arr[p]) dup = true;
                if (!dup) sv += u[arr[p]*(mul*idim) + k*idim + i];
            }
            usum[t] = sv;
        }
    } else if (mono < NMONO3 + NMONO2) {
        if (t < 23) {
            int A, B; decode2(mono - NMONO3, A, B);
            const float* u; int mul, idim, k, i;
            if (t < 2)      { u = u2_0e; mul = 2; idim = 1; k = t; i = 0; }
            else if (t < 8) { u = u2_1o; mul = 2; idim = 3; int r = t - 2; k = r / 3; i = r % 3; }
            else            { u = u2_2e; mul = 3; idim = 5; int r = t - 8; k = r / 5; i = r % 5; }
            float sv = u[(A*9+B)*(mul*idim) + k*idim + i];
            if (A != B) sv += u[(B*9+A)*(mul*idim) + k*idim + i];
            usum[t] = sv;
        }
    } else {
        if (t < 9) {
            int A = mono - (NMONO3 + NMONO2);
            float sv;
            if (t == 0)      sv = u1_0e[A];
            else if (t < 4)  sv = u1_1o[A*3 + (t-1)];
            else             sv = u1_2e[A*5 + (t-4)];
            usum[t] = sv;
        }
    }
    __syncthreads();

    // Stage 2: contract with per-species weights -> 9 outputs per (s, mono, c).
    float o[9];
    if (mono < NMONO3) {
        float v = 0.f;
        #pragma unroll
        for (int k = 0; k < 4; k++) v += usum[k] * w3_0e[(s*4+k)*NC + c];
        o[0] = v;
        #pragma unroll
        for (int i = 0; i < 3; i++) {
            v = 0.f;
            #pragma unroll
            for (int k = 0; k < 6; k++) v += usum[4 + k*3 + i] * w3_1o[(s*6+k)*NC + c];
            o[1+i] = v;
        }
        #pragma unroll
        for (int i = 0; i < 5; i++) {
            v = 0.f;
            #pragma unroll
            for (int k = 0; k < 8; k++) v += usum[22 + k*5 + i] * w3_2e[(s*8+k)*NC + c];
            o[4+i] = v;
        }
    } else if (mono < NMONO3 + NMONO2) {
        float v = 0.f;
        #pragma unroll
        for (int k = 0; k < 2; k++) v += usum[k] * w2_0e[(s*2+k)*NC + c];
        o[0] = v;
        #pragma unroll
        for (int i = 0; i < 3; i++) {
            v = 0.f;
            #pragma unroll
            for (int k = 0; k < 2; k++) v += usum[2 + k*3 + i] * w2_1o[(s*2+k)*NC + c];
            o[1+i] = v;
        }
        #pragma unroll
        for (int i = 0; i < 5; i++) {
            v = 0.f;
            #pragma unroll
            for (int k = 0; k < 3; k++) v += usum[8 + k*5 + i] * w2_2e[(s*3+k)*NC + c];
            o[4+i] = v;
        }
    } else {
        o[0] = usum[0] * w1_0e[s*NC + c];
        #pragma unroll
        for (int i = 0; i < 3; i++) o[1+i] = usum[1+i] * w1_1o[s*NC + c];
        #pragma unroll
        for (int i = 0; i < 5; i++) o[4+i] = usum[4+i] * w1_2e[s*NC + c];
    }

    const size_t base = (size_t)(s*NMONO + mono)*NC + c;
    #pragma unroll
    for (int q = 0; q < 8; q++) uwA[base*8 + q] = o[q];
    uwB[base] = o[8];
}

// Counting sort of nodes by species + block assignment table. One block, 1024 threads.
__global__ __launch_bounds__(1024) void build_groups(
    const int* __restrict__ index,
    int* __restrict__ perm,      // [NN]
    int* __restrict__ offs,      // [NS+1]
    int* __restrict__ blockmap)  // [MAXBLK*2]: (species, chunk) or (-1, 0)
{
    __shared__ int cnt[NS], pos[NS];
    const int t = threadIdx.x;
    if (t < NS) cnt[t] = 0;
    __syncthreads();
    const int s = index[t];
    atomicAdd(&cnt[s], 1);
    __syncthreads();
    if (t == 0) {
        int o = 0;
        for (int i = 0; i < NS; i++) { offs[i] = o; pos[i] = o; o += cnt[i]; }
        offs[NS] = o;
        int b = 0;
        for (int i = 0; i < NS; i++) {
            int nb = (cnt[i] + NPB - 1) / NPB;
            for (int j = 0; j < nb; j++) { blockmap[2*b] = i; blockmap[2*b+1] = j; b++; }
        }
        for (; b < MAXBLK; b++) { blockmap[2*b] = -1; blockmap[2*b+1] = 0; }
    }
    __syncthreads();
    const int r = atomicAdd(&pos[s], 1);
    perm[r] = t;
}

__global__ __launch_bounds__(256) void symcon_main(
    const float* __restrict__ x,
    const int* __restrict__ perm, const int* __restrict__ offs,
    const int* __restrict__ blockmap,
    const float* __restrict__ uwA, const float* __restrict__ uwB,
    float* __restrict__ out)
{
    __shared__ float lx[256][11];   // [tid][d]; stride 11 dwords -> conflict-free; [9]=1.0 sentinel
    __shared__ int   abj[NMONO];    // packed (a<<8)|(b<<4)|j, broadcast-read

    const int tid = threadIdx.x;
    const int c   = tid & 127;
    const int h   = tid >> 7;       // which of the block's 2 nodes this thread owns

    // Populate the monomial index table (mono order MUST match precompute_uw).
    if (tid < NMONO) {
        int a, b, j;
        if (tid < NMONO3)               { decode3(tid, a, b, j); }
        else if (tid < NMONO3 + NMONO2) { decode2(tid - NMONO3, a, b); j = 9; }
        else                            { a = tid - (NMONO3 + NMONO2); b = 9; j = 9; }
        abj[tid] = (a << 8) | (b << 4) | j;
    }

    const int s     = blockmap[2*blockIdx.x];
    const int chunk = blockmap[2*blockIdx.x + 1];
    if (s < 0) return;
    const int gbeg = offs[s], gend = offs[s+1];
    const int pidx = gbeg + chunk*NPB + h;
    const bool valid = (pidx < gend);
    const int node = perm[valid ? pidx : gbeg];

    {
        const float* xp = x + ((size_t)node*NC + c)*9;
        #pragma unroll
        for (int d = 0; d < 9; d++) lx[tid][d] = xp[d];
        lx[tid][9] = 1.0f;
    }
    __syncthreads();

    float acc[9];
    #pragma unroll
    for (int q = 0; q < 9; q++) acc[q] = 0.f;

    const float* pA = uwA + ((size_t)s*NMONO*NC + c) * 8;   // +NC*8 per mono
    const float* pB = uwB +  (size_t)s*NMONO*NC + c;        // +NC   per mono
    const float* myx = &lx[tid][0];

    #pragma unroll 3
    for (int m = 0; m < NMONO; m++) {
        const int e = abj[m];
        const float pa = myx[(e >> 8) & 15];
        const float pb = myx[(e >> 4) & 15];
        const float pj = myx[e & 15];
        const float p  = pa * pb * pj;
        const float4 f0 = *(const float4*)(pA);
        const float4 f1 = *(const float4*)(pA + 4);
        const float  fb = *pB;
        acc[0] += f0.x*p; acc[1] += f0.y*p; acc[2] += f0.z*p; acc[3] += f0.w*p;
        acc[4] += f1.x*p; acc[5] += f1.y*p; acc[6] += f1.z*p; acc[7] += f1.w*p;
        acc[8] += fb*p;
        pA += NC*8; pB += NC;
    }

    if (valid) {
        // output row: [0e: c][1o: 128 + c*3+i][2e: 512 + c*5+i], row stride 1152
        float* orow = out + (size_t)node * 1152;
        orow[c] = acc[0];
        #pragma unroll
        for (int i = 0; i < 3; i++) orow[128 + c*3 + i] = acc[1+i];
        #pragma unroll
        for (int i = 0; i < 5; i++) orow[512 + c*5 + i] = acc[4+i];
    }
}

extern "C" void kernel_launch(void* const* d_in, const int* in_sizes, int n_in,
                              void* d_out, int out_size, void* d_ws, size_t ws_size,
                              hipStream_t stream)
{
    // setup_inputs() dict order: x, then (u,w) interleaved for order 1..3 x {0e,1o,2e}, then index.
    const float* x     = (const float*)d_in[0];
    const float* u1_0e = (const float*)d_in[1];
    const float* w1_0e = (const float*)d_in[2];
    const float* u1_1o = (const float*)d_in[3];
    const float* w1_1o = (const float*)d_in[4];
    const float* u1_2e = (const float*)d_in[5];
    const float* w1_2e = (const float*)d_in[6];
    const float* u2_0e = (const float*)d_in[7];
    const float* w2_0e = (const float*)d_in[8];
    const float* u2_1o = (const float*)d_in[9];
    const float* w2_1o = (const float*)d_in[10];
    const float* u2_2e = (const float*)d_in[11];
    const float* w2_2e = (const float*)d_in[12];
    const float* u3_0e = (const float*)d_in[13];
    const float* w3_0e = (const float*)d_in[14];
    const float* u3_1o = (const float*)d_in[15];
    const float* w3_1o = (const float*)d_in[16];
    const float* u3_2e = (const float*)d_in[17];
    const float* w3_2e = (const float*)d_in[18];
    const int*   index = (const int*)d_in[19];
    float* out = (float*)d_out;

    float* uwA = (float*)d_ws;                          // [S][219][128][8] floats
    float* uwB = uwA + (size_t)NS*NMONO*NC*8;           // [S][219][128]    floats
    int*   perm     = (int*)(uwB + (size_t)NS*NMONO*NC);// [NN]
    int*   offs     = perm + NN;                        // [NS+1]
    int*   blockmap = offs + (NS+1);                    // [MAXBLK*2]
    // total ws use ~= 10.1 MB + ~8 KB

    hipLaunchKernelGGL(build_groups, dim3(1), dim3(NN), 0, stream,
        index, perm, offs, blockmap);

    hipLaunchKernelGGL(precompute_uw, dim3(NS*NMONO), dim3(128), 0, stream,
        u1_0e, w1_0e, u1_1o, w1_1o, u1_2e, w1_2e,
        u2_0e, w2_0e, u2_1o, w2_1o, u2_2e, w2_2e,
        u3_0e, w3_0e, u3_1o, w3_1o, u3_2e, w3_2e, uwA, uwB);

    hipLaunchKernelGGL(symcon_main, dim3(MAXBLK), dim3(256), 0, stream,
        x, perm, offs, blockmap, uwA, uwB, out);
}

// Round 5
// 158.125 us; speedup vs baseline: 10.1526x; 1.0665x over previous
//
#include <hip/hip_runtime.h>

// Symmetric contraction (MACE-style), N=1024 nodes, C=128 ch, D=9, S=10 species, corr=3.
//   out[n,c,i] = sum_m Uw[index[n], m, i, c] * mono_m(x[n,c,:]),  m over 219 symmetric monomials.
// R2: static 219-unroll spilled (VGPR 256, 1.5 GB scratch, 1511 us).
// R4: runtime loop, 61 us, latency-bound: Occ 12.8%, VALU 24%, FETCH 42 MB (XCD-spread L2 misses).
// R5 (this): 1024-thr blocks (2 nodes x 4 mono-quarters -> 32 waves/CU), XCD-local blockmap,
//   pair-group loop (shared p2, sentinel lx[*][9]=1 folds deg1/2 into deg3 body),
//   constexpr mono/pair tables (no decode scans), parallel build_groups, float4 uw stores.

#define NMONO 219
#define NPAIR 54
#define NN 1024
#define NC 128
#define NS 10
#define NPB 2
#define PADBLK 528   // 8 * 66 >= worst-case chunk count (<=517), padded for the %8 XCD layout

struct Tables {
    int mt[NMONO];          // (a<<8)|(b<<4)|j ; j==9 -> deg2, b==9 -> deg1 (sentinel index)
    int pair_ab[NPAIR];     // (a<<4)|b, b in [a,9]
    int pair_m0[NPAIR + 1]; // starting mono of each pair (monos contiguous across pairs)
    int qs[5];              // pair-index split points for 4 quarters (balanced by mono count)
};

constexpr Tables make_tables() {
    Tables T{};
    int m = 0, pg = 0;
    for (int a = 0; a < 9; a++)
        for (int b = a; b < 10; b++) {
            T.pair_ab[pg] = (a << 4) | b;
            T.pair_m0[pg] = m;
            for (int j = b; j < 10; j++) { T.mt[m] = (a << 8) | (b << 4) | j; m++; }
            pg++;
        }
    T.pair_m0[NPAIR] = m;   // 219
    T.qs[0] = 0; T.qs[4] = NPAIR;
    for (int q = 1; q < 4; q++) {
        int best = 0; long bestd = 1L << 40;
        for (int p = 0; p <= NPAIR; p++) {
            long d = 4L * T.pair_m0[p] - 219L * q;
            if (d < 0) d = -d;
            if (d < bestd) { bestd = d; best = p; }
        }
        T.qs[q] = best;
    }
    return T;
}

__device__ __constant__ const Tables TBL = make_tables();

__global__ __launch_bounds__(128) void precompute_uw(
    const float* __restrict__ u1_0e, const float* __restrict__ w1_0e,
    const float* __restrict__ u1_1o, const float* __restrict__ w1_1o,
    const float* __restrict__ u1_2e, const float* __restrict__ w1_2e,
    const float* __restrict__ u2_0e, const float* __restrict__ w2_0e,
    const float* __restrict__ u2_1o, const float* __restrict__ w2_1o,
    const float* __restrict__ u2_2e, const float* __restrict__ w2_2e,
    const float* __restrict__ u3_0e, const float* __restrict__ w3_0e,
    const float* __restrict__ u3_1o, const float* __restrict__ w3_1o,
    const float* __restrict__ u3_2e, const float* __restrict__ w3_2e,
    float* __restrict__ uwA, float* __restrict__ uwB)
{
    const int blk  = blockIdx.x;
    const int s    = blk / NMONO;
    const int mono = blk % NMONO;
    const int c    = threadIdx.x;   // 128 channels
    const int t    = threadIdx.x;
    __shared__ float usum[64];

    const int e = TBL.mt[mono];
    const int A = (e >> 8) & 15, B = (e >> 4) & 15, J = e & 15;
    const bool deg3 = (J < 9);
    const bool deg1 = (B == 9);

    // Stage 1: symmetrized u sums (independent of s and c).
    if (deg3) {
        if (t < 62) {
            const float* u; int mul, idim, k, i;
            if (t < 4)       { u = u3_0e; mul = 4; idim = 1; k = t; i = 0; }
            else if (t < 22) { u = u3_1o; mul = 6; idim = 3; int r = t - 4;  k = r / 3; i = r % 3; }
            else             { u = u3_2e; mul = 8; idim = 5; int r = t - 22; k = r / 5; i = r % 5; }
            int arr[6] = { A*81+B*9+J, A*81+J*9+B, B*81+A*9+J, B*81+J*9+A, J*81+A*9+B, J*81+B*9+A };
            float sv = 0.f;
            for (int p = 0; p < 6; p++) {
                bool dup = false;
                for (int q = 0; q < p; q++) if (arr[q] == arr[p]) dup = true;
                if (!dup) sv += u[arr[p]*(mul*idim) + k*idim + i];
            }
            usum[t] = sv;
        }
    } else if (!deg1) {             // deg2: indices (A,B)
        if (t < 23) {
            const float* u; int mul, idim, k, i;
            if (t < 2)      { u = u2_0e; mul = 2; idim = 1; k = t; i = 0; }
            else if (t < 8) { u = u2_1o; mul = 2; idim = 3; int r = t - 2; k = r / 3; i = r % 3; }
            else            { u = u2_2e; mul = 3; idim = 5; int r = t - 8; k = r / 5; i = r % 5; }
            float sv = u[(A*9+B)*(mul*idim) + k*idim + i];
            if (A != B) sv += u[(B*9+A)*(mul*idim) + k*idim + i];
            usum[t] = sv;
        }
    } else {                        // deg1: index A
        if (t < 9) {
            float sv;
            if (t == 0)      sv = u1_0e[A];
            else if (t < 4)  sv = u1_1o[A*3 + (t-1)];
            else             sv = u1_2e[A*5 + (t-4)];
            usum[t] = sv;
        }
    }
    __syncthreads();

    // Stage 2: contract with per-species weights -> 9 outputs per (s, mono, c).
    float o[9];
    if (deg3) {
        float v = 0.f;
        #pragma unroll
        for (int k = 0; k < 4; k++) v += usum[k] * w3_0e[(s*4+k)*NC + c];
        o[0] = v;
        #pragma unroll
        for (int i = 0; i < 3; i++) {
            v = 0.f;
            #pragma unroll
            for (int k = 0; k < 6; k++) v += usum[4 + k*3 + i] * w3_1o[(s*6+k)*NC + c];
            o[1+i] = v;
        }
        #pragma unroll
        for (int i = 0; i < 5; i++) {
            v = 0.f;
            #pragma unroll
            for (int k = 0; k < 8; k++) v += usum[22 + k*5 + i] * w3_2e[(s*8+k)*NC + c];
            o[4+i] = v;
        }
    } else if (!deg1) {
        float v = 0.f;
        #pragma unroll
        for (int k = 0; k < 2; k++) v += usum[k] * w2_0e[(s*2+k)*NC + c];
        o[0] = v;
        #pragma unroll
        for (int i = 0; i < 3; i++) {
            v = 0.f;
            #pragma unroll
            for (int k = 0; k < 2; k++) v += usum[2 + k*3 + i] * w2_1o[(s*2+k)*NC + c];
            o[1+i] = v;
        }
        #pragma unroll
        for (int i = 0; i < 5; i++) {
            v = 0.f;
            #pragma unroll
            for (int k = 0; k < 3; k++) v += usum[8 + k*5 + i] * w2_2e[(s*3+k)*NC + c];
            o[4+i] = v;
        }
    } else {
        o[0] = usum[0] * w1_0e[s*NC + c];
        #pragma unroll
        for (int i = 0; i < 3; i++) o[1+i] = usum[1+i] * w1_1o[s*NC + c];
        #pragma unroll
        for (int i = 0; i < 5; i++) o[4+i] = usum[4+i] * w1_2e[s*NC + c];
    }

    const size_t base = (size_t)(s*NMONO + mono)*NC + c;
    float4 lo; lo.x = o[0]; lo.y = o[1]; lo.z = o[2]; lo.w = o[3];
    float4 hi; hi.x = o[4]; hi.y = o[5]; hi.z = o[6]; hi.w = o[7];
    *(float4*)(uwA + base*8)     = lo;
    *(float4*)(uwA + base*8 + 4) = hi;
    uwB[base] = o[8];
}

// Counting sort of nodes by species + XCD-local blockmap. One block, 1024 threads.
// blockmap position p (p%8 == x) holds XCD x's contiguous range of species-chunks, so
// consecutive blockIdx (round-robin over 8 XCDs) keep each species slice in ONE L2.
__global__ __launch_bounds__(1024) void build_groups(
    const int* __restrict__ index,
    int* __restrict__ perm,      // [NN]
    int* __restrict__ offs,      // [NS+1]
    int* __restrict__ blockmap)  // [PADBLK*2]: (species, chunk) or (-1, 0)
{
    __shared__ int cnt[NS], pos[NS], nbstart[NS+1];
    __shared__ int sh_nch;
    const int t = threadIdx.x;
    if (t < NS) cnt[t] = 0;
    __syncthreads();
    const int s = index[t];
    atomicAdd(&cnt[s], 1);
    __syncthreads();
    if (t == 0) {
        int o = 0, g = 0;
        for (int i = 0; i < NS; i++) {
            offs[i] = o; pos[i] = o; o += cnt[i];
            nbstart[i] = g; g += (cnt[i] + NPB - 1) / NPB;
        }
        offs[NS] = o; nbstart[NS] = g; sh_nch = g;
    }
    __syncthreads();
    const int Nch = sh_nch;
    for (int p = t; p < PADBLK; p += 1024) { blockmap[2*p] = -1; blockmap[2*p+1] = 0; }
    __syncthreads();
    if (t < Nch) {
        const int g = t;                       // global chunk id (species-major)
        const int q = Nch >> 3, r = Nch & 7;
        int x = 0, stx = 0;
        for (int xx = 0; xx < 8; xx++) {       // find XCD segment containing g
            const int cx = q + (xx < r ? 1 : 0);
            if (g < stx + cx) { x = xx; break; }
            stx += cx;
        }
        const int p = x + 8 * (g - stx);       // bijective: chunk g -> block position p
        int sp = 0;
        while (g >= nbstart[sp+1]) sp++;
        blockmap[2*p]   = sp;
        blockmap[2*p+1] = g - nbstart[sp];
    }
    const int r2 = atomicAdd(&pos[s], 1);
    perm[r2] = t;
}

// Block = 1024 threads: quarter z (0..3) x node h (0..1) x channel c (0..127).
// Each (z,h,c) thread accumulates its quarter's monomials; quarters LDS-reduced at the end.
__global__ __launch_bounds__(1024, 8) void symcon_main(
    const float* __restrict__ x,
    const int* __restrict__ perm, const int* __restrict__ offs,
    const int* __restrict__ blockmap,
    const float* __restrict__ uwA, const float* __restrict__ uwB,
    float* __restrict__ out)
{
    __shared__ float lx[256][11];      // [h*128+c][d], stride 11 -> conflict-free; [9]=1.0 sentinel
    __shared__ float red[3][256][9];   // quarter partial sums

    const int tid = threadIdx.x;
    const int z   = tid >> 8;
    const int hc  = tid & 255;
    const int h   = hc >> 7;
    const int c   = tid & 127;

    const int s     = blockmap[2*blockIdx.x];
    const int chunk = blockmap[2*blockIdx.x + 1];
    if (s < 0) return;                 // block-uniform
    const int gbeg = offs[s], gend = offs[s+1];
    const int p0   = gbeg + chunk*NPB;
    const int node0 = perm[p0];
    const bool v1   = (p0 + 1 < gend);
    const int node1 = perm[v1 ? p0 + 1 : p0];

    // Cooperative coalesced staging of both nodes' x rows (1152 floats each).
    for (int f = tid; f < 1152; f += 1024) {
        const int ch = f / 9;
        const int d  = f - ch*9;
        lx[ch][d]     = x[(size_t)node0*1152 + f];
        lx[128+ch][d] = x[(size_t)node1*1152 + f];
    }
    if (tid < 256) lx[tid][9] = 1.0f;
    __syncthreads();

    const float* lxr = &lx[hc][0];
    const int pg0 = TBL.qs[z], pg1 = TBL.qs[z+1];
    const int m0  = TBL.pair_m0[pg0];
    const float* pA = uwA + ((size_t)(s*NMONO + m0)*NC + c) * 8;
    const float* pB = uwB +  (size_t)(s*NMONO + m0)*NC + c;

    float acc[9];
    #pragma unroll
    for (int i = 0; i < 9; i++) acc[i] = 0.f;

    for (int pg = pg0; pg < pg1; ++pg) {
        const int ab = TBL.pair_ab[pg];
        const int a = ab >> 4, b = ab & 15;
        const float p2 = lxr[a] * lxr[b];
        for (int j = b; j < 10; ++j) {          // j==9 hits the sentinel (deg2/deg1 folded in)
            const float p  = p2 * lxr[j];
            const float4 f0 = *(const float4*)(pA);
            const float4 f1 = *(const float4*)(pA + 4);
            const float  fb = *pB;
            acc[0] += f0.x*p; acc[1] += f0.y*p; acc[2] += f0.z*p; acc[3] += f0.w*p;
            acc[4] += f1.x*p; acc[5] += f1.y*p; acc[6] += f1.z*p; acc[7] += f1.w*p;
            acc[8] += fb*p;
            pA += NC*8; pB += NC;
        }
    }

    if (z > 0) {
        #pragma unroll
        for (int i = 0; i < 9; i++) red[z-1][hc][i] = acc[i];
    }
    __syncthreads();
    if (z == 0) {
        #pragma unroll
        for (int i = 0; i < 9; i++)
            acc[i] += red[0][hc][i] + red[1][hc][i] + red[2][hc][i];
        if (h == 0 || v1) {
            const int node = h ? node1 : node0;
            float* orow = out + (size_t)node * 1152;   // [0e: c][1o: 128+c*3+i][2e: 512+c*5+i]
            orow[c] = acc[0];
            #pragma unroll
            for (int i = 0; i < 3; i++) orow[128 + c*3 + i] = acc[1+i];
            #pragma unroll
            for (int i = 0; i < 5; i++) orow[512 + c*5 + i] = acc[4+i];
        }
    }
}

extern "C" void kernel_launch(void* const* d_in, const int* in_sizes, int n_in,
                              void* d_out, int out_size, void* d_ws, size_t ws_size,
                              hipStream_t stream)
{
    const float* x     = (const float*)d_in[0];
    const float* u1_0e = (const float*)d_in[1];
    const float* w1_0e = (const float*)d_in[2];
    const float* u1_1o = (const float*)d_in[3];
    const float* w1_1o = (const float*)d_in[4];
    const float* u1_2e = (const float*)d_in[5];
    const float* w1_2e = (const float*)d_in[6];
    const float* u2_0e = (const float*)d_in[7];
    const float* w2_0e = (const float*)d_in[8];
    const float* u2_1o = (const float*)d_in[9];
    const float* w2_1o = (const float*)d_in[10];
    const float* u2_2e = (const float*)d_in[11];
    const float* w2_2e = (const float*)d_in[12];
    const float* u3_0e = (const float*)d_in[13];
    const float* w3_0e = (const float*)d_in[14];
    const float* u3_1o = (const float*)d_in[15];
    const float* w3_1o = (const float*)d_in[16];
    const float* u3_2e = (const float*)d_in[17];
    const float* w3_2e = (const float*)d_in[18];
    const int*   index = (const int*)d_in[19];
    float* out = (float*)d_out;

    float* uwA = (float*)d_ws;                           // [S][219][128][8] floats
    float* uwB = uwA + (size_t)NS*NMONO*NC*8;            // [S][219][128]    floats
    int*   perm     = (int*)(uwB + (size_t)NS*NMONO*NC); // [NN]
    int*   offs     = perm + NN;                         // [NS+1]
    int*   blockmap = offs + (NS+1);                     // [PADBLK*2]

    hipLaunchKernelGGL(build_groups, dim3(1), dim3(NN), 0, stream,
        index, perm, offs, blockmap);

    hipLaunchKernelGGL(precompute_uw, dim3(NS*NMONO), dim3(128), 0, stream,
        u1_0e, w1_0e, u1_1o, w1_1o, u1_2e, w1_2e,
        u2_0e, w2_0e, u2_1o, w2_1o, u2_2e, w2_2e,
        u3_0e, w3_0e, u3_1o, w3_1o, u3_2e, w3_2e, uwA, uwB);

    hipLaunchKernelGGL(symcon_main, dim3(PADBLK), dim3(1024), 0, stream,
        x, perm, offs, blockmap, uwA, uwB, out);
}

// Round 6
// 149.519 us; speedup vs baseline: 10.7370x; 1.0576x over previous
//
#include <hip/hip_runtime.h>

// Symmetric contraction (MACE-style), N=1024 nodes, C=128 ch, D=9, S=10 species, corr=3.
//   out[n,c,i] = sum_m Uw[index[n], m, i, c] * mono_m(x[n,c,:]),  m over 219 symmetric monomials.
// R2: static 219-unroll spilled (VGPR 256, 1.5 GB scratch, 1511 us).
// R4: runtime loop: 61 us, latency-bound (Occ 12.8, VALU 24, FETCH 42 MB XCD-spread).
// R5: 1024-thr + XCD-local map: 56 us. FETCH fixed (10 MB) but launch_bounds(1024,8) -> VGPR 16,
//     zero ILP, VALU 18% -> pure L2-latency stalls. Precompute re-loads w-rows per mono (~13M loads).
// R6 (this): symcon = 512 thr (4 z-quarters x 128 c), 4 NODES PER THREAD (36 FMA per 36B fetch,
//     L2 requests 533->275 MB), launch_bounds(512,4) (VGPR cap 128), explicit 2-slot pipeline,
//     x packed in LDS as [c][d][4nodes] -> one ds_read_b128 per index. Precompute split into
//     u_sym (219x64, once) + uw_fold (w-regs loaded once per (s,c), 16 monos per block).

#define NMONO 219
#define NN 1024
#define NC 128
#define NS 10
#define NPB 4
#define PADBLK 272   // 8*34 >= worst-case chunk count (<=266), padded for %8 XCD layout
#define FOLD_CHUNK 16
#define NCHUNKF ((NMONO + FOLD_CHUNK - 1) / FOLD_CHUNK)   // 14

struct Tables { int mt[NMONO]; };   // (a<<8)|(b<<4)|j ; j==9 -> deg2 ; b==9 -> deg1 (sentinel)

constexpr Tables make_tables() {
    Tables T{};
    int m = 0;
    for (int a = 0; a < 9; a++)
        for (int b = a; b < 10; b++)
            for (int j = b; j < 10; j++) { T.mt[m] = (a << 8) | (b << 4) | j; m++; }
    return T;
}
__device__ __constant__ const Tables TBL = make_tables();

// ---------- Kernel 1: symmetrized u-sums, one block per monomial (runs once, tiny) ----------
__global__ __launch_bounds__(64) void u_sym(
    const float* __restrict__ u1_0e, const float* __restrict__ u1_1o, const float* __restrict__ u1_2e,
    const float* __restrict__ u2_0e, const float* __restrict__ u2_1o, const float* __restrict__ u2_2e,
    const float* __restrict__ u3_0e, const float* __restrict__ u3_1o, const float* __restrict__ u3_2e,
    float* __restrict__ usumAll)   // [NMONO][64]
{
    const int mono = blockIdx.x;
    const int t = threadIdx.x;
    const int e = TBL.mt[mono];
    const int A = (e >> 8) & 15, B = (e >> 4) & 15, J = e & 15;
    float sv = 0.f;
    if (J < 9) {                       // deg3
        if (t < 62) {
            const float* u; int mul, idim, k, i;
            if (t < 4)       { u = u3_0e; mul = 4; idim = 1; k = t; i = 0; }
            else if (t < 22) { u = u3_1o; mul = 6; idim = 3; int r = t - 4;  k = r / 3; i = r % 3; }
            else             { u = u3_2e; mul = 8; idim = 5; int r = t - 22; k = r / 5; i = r % 5; }
            int arr[6] = { A*81+B*9+J, A*81+J*9+B, B*81+A*9+J, B*81+J*9+A, J*81+A*9+B, J*81+B*9+A };
            for (int p = 0; p < 6; p++) {
                bool dup = false;
                for (int q = 0; q < p; q++) if (arr[q] == arr[p]) dup = true;
                if (!dup) sv += u[arr[p]*(mul*idim) + k*idim + i];
            }
        }
    } else if (B < 9) {                // deg2 (A,B)
        if (t < 23) {
            const float* u; int mul, idim, k, i;
            if (t < 2)      { u = u2_0e; mul = 2; idim = 1; k = t; i = 0; }
            else if (t < 8) { u = u2_1o; mul = 2; idim = 3; int r = t - 2; k = r / 3; i = r % 3; }
            else            { u = u2_2e; mul = 3; idim = 5; int r = t - 8; k = r / 5; i = r % 5; }
            sv = u[(A*9+B)*(mul*idim) + k*idim + i];
            if (A != B) sv += u[(B*9+A)*(mul*idim) + k*idim + i];
        }
    } else {                           // deg1 (A)
        if (t < 9) {
            if (t == 0)      sv = u1_0e[A];
            else if (t < 4)  sv = u1_1o[A*3 + (t-1)];
            else             sv = u1_2e[A*5 + (t-4)];
        }
    }
    usumAll[mono*64 + t] = sv;
}

// ---------- Kernel 2: fold with per-species weights; w-rows live in registers ----------
__global__ __launch_bounds__(128) void uw_fold(
    const float* __restrict__ w1_0e, const float* __restrict__ w1_1o, const float* __restrict__ w1_2e,
    const float* __restrict__ w2_0e, const float* __restrict__ w2_1o, const float* __restrict__ w2_2e,
    const float* __restrict__ w3_0e, const float* __restrict__ w3_1o, const float* __restrict__ w3_2e,
    const float* __restrict__ usumAll,
    float* __restrict__ uwA, float* __restrict__ uwB)
{
    const int s  = blockIdx.x / NCHUNKF;
    const int m0 = (blockIdx.x % NCHUNKF) * FOLD_CHUNK;
    const int c  = threadIdx.x;
    __shared__ float us[FOLD_CHUNK][64];

    for (int f = c; f < FOLD_CHUNK*64; f += 128) {
        const int mm = f >> 6, sl = f & 63, m = m0 + mm;
        us[mm][sl] = (m < NMONO) ? usumAll[m*64 + sl] : 0.f;
    }
    __syncthreads();

    float W30[4], W31[6], W32[8], W20[2], W21[2], W22[3];
    #pragma unroll
    for (int k = 0; k < 4; k++) W30[k] = w3_0e[(s*4+k)*NC + c];
    #pragma unroll
    for (int k = 0; k < 6; k++) W31[k] = w3_1o[(s*6+k)*NC + c];
    #pragma unroll
    for (int k = 0; k < 8; k++) W32[k] = w3_2e[(s*8+k)*NC + c];
    #pragma unroll
    for (int k = 0; k < 2; k++) W20[k] = w2_0e[(s*2+k)*NC + c];
    #pragma unroll
    for (int k = 0; k < 2; k++) W21[k] = w2_1o[(s*2+k)*NC + c];
    #pragma unroll
    for (int k = 0; k < 3; k++) W22[k] = w2_2e[(s*3+k)*NC + c];
    const float W10 = w1_0e[s*NC + c], W11 = w1_1o[s*NC + c], W12 = w1_2e[s*NC + c];

    for (int mm = 0; mm < FOLD_CHUNK; mm++) {
        const int m = m0 + mm;
        if (m >= NMONO) break;
        const int e = TBL.mt[m];
        const int B = (e >> 4) & 15, J = e & 15;
        float o[9];
        if (J < 9) {
            float v = 0.f;
            #pragma unroll
            for (int k = 0; k < 4; k++) v += us[mm][k] * W30[k];
            o[0] = v;
            #pragma unroll
            for (int i = 0; i < 3; i++) {
                v = 0.f;
                #pragma unroll
                for (int k = 0; k < 6; k++) v += us[mm][4 + k*3 + i] * W31[k];
                o[1+i] = v;
            }
            #pragma unroll
            for (int i = 0; i < 5; i++) {
                v = 0.f;
                #pragma unroll
                for (int k = 0; k < 8; k++) v += us[mm][22 + k*5 + i] * W32[k];
                o[4+i] = v;
            }
        } else if (B < 9) {
            float v = 0.f;
            #pragma unroll
            for (int k = 0; k < 2; k++) v += us[mm][k] * W20[k];
            o[0] = v;
            #pragma unroll
            for (int i = 0; i < 3; i++) {
                v = 0.f;
                #pragma unroll
                for (int k = 0; k < 2; k++) v += us[mm][2 + k*3 + i] * W21[k];
                o[1+i] = v;
            }
            #pragma unroll
            for (int i = 0; i < 5; i++) {
                v = 0.f;
                #pragma unroll
                for (int k = 0; k < 3; k++) v += us[mm][8 + k*5 + i] * W22[k];
                o[4+i] = v;
            }
        } else {
            o[0] = us[mm][0] * W10;
            #pragma unroll
            for (int i = 0; i < 3; i++) o[1+i] = us[mm][1+i] * W11;
            #pragma unroll
            for (int i = 0; i < 5; i++) o[4+i] = us[mm][4+i] * W12;
        }
        const size_t base = (size_t)(s*NMONO + m)*NC + c;
        float4 lo; lo.x = o[0]; lo.y = o[1]; lo.z = o[2]; lo.w = o[3];
        float4 hi; hi.x = o[4]; hi.y = o[5]; hi.z = o[6]; hi.w = o[7];
        *(float4*)(uwA + base*8)     = lo;
        *(float4*)(uwA + base*8 + 4) = hi;
        uwB[base] = o[8];
    }
}

// ---------- Kernel 3: species sort + XCD-local blockmap (proven in R5: FETCH 42->10 MB) ----------
__global__ __launch_bounds__(1024) void build_groups(
    const int* __restrict__ index,
    int* __restrict__ perm, int* __restrict__ offs, int* __restrict__ blockmap)
{
    __shared__ int cnt[NS], pos[NS], nbstart[NS+1];
    __shared__ int sh_nch;
    const int t = threadIdx.x;
    if (t < NS) cnt[t] = 0;
    __syncthreads();
    const int s = index[t];
    atomicAdd(&cnt[s], 1);
    __syncthreads();
    if (t == 0) {
        int o = 0, g = 0;
        for (int i = 0; i < NS; i++) {
            offs[i] = o; pos[i] = o; o += cnt[i];
            nbstart[i] = g; g += (cnt[i] + NPB - 1) / NPB;
        }
        offs[NS] = o; nbstart[NS] = g; sh_nch = g;
    }
    __syncthreads();
    const int Nch = sh_nch;
    for (int p = t; p < PADBLK; p += 1024) { blockmap[2*p] = -1; blockmap[2*p+1] = 0; }
    __syncthreads();
    if (t < Nch) {
        const int g = t;
        const int q = Nch >> 3, r = Nch & 7;
        int x = 0, stx = 0;
        for (int xx = 0; xx < 8; xx++) {
            const int cx = q + (xx < r ? 1 : 0);
            if (g < stx + cx) { x = xx; break; }
            stx += cx;
        }
        const int p = x + 8 * (g - stx);       // bijective chunk -> block position
        int sp = 0;
        while (g >= nbstart[sp+1]) sp++;
        blockmap[2*p]   = sp;
        blockmap[2*p+1] = g - nbstart[sp];
    }
    const int r2 = atomicAdd(&pos[s], 1);
    perm[r2] = t;
}

// ---------- Kernel 4: main contraction ----------
// 512 thr = z-quarter (0..3) x c (0..127); each thread: 4 nodes x ~55 monomials.
// lx4[c][d][q]: 4 nodes packed -> one ds_read_b128 yields x_d for all 4 nodes.
#define FMA_NODE(Q, P, F0, F1, FB)                                          \
    acc[Q][0] += F0.x*(P); acc[Q][1] += F0.y*(P); acc[Q][2] += F0.z*(P);    \
    acc[Q][3] += F0.w*(P); acc[Q][4] += F1.x*(P); acc[Q][5] += F1.y*(P);    \
    acc[Q][6] += F1.z*(P); acc[Q][7] += F1.w*(P); acc[Q][8] += FB*(P);

#define CONSUME(MM, F0, F1, FB)                                             \
    { const int e = TBL.mt[MM];                                             \
      const float4 xa = *(const float4*)&lx4[c44 + ((e>>8)&15)*4];          \
      const float4 xb = *(const float4*)&lx4[c44 + ((e>>4)&15)*4];          \
      const float4 xj = *(const float4*)&lx4[c44 + (e&15)*4];               \
      FMA_NODE(0, xa.x*xb.x*xj.x, F0, F1, FB)                               \
      FMA_NODE(1, xa.y*xb.y*xj.y, F0, F1, FB)                               \
      FMA_NODE(2, xa.z*xb.z*xj.z, F0, F1, FB)                               \
      FMA_NODE(3, xa.w*xb.w*xj.w, F0, F1, FB) }

__global__ __launch_bounds__(512, 4) void symcon_main(
    const float* __restrict__ x,
    const int* __restrict__ perm, const int* __restrict__ offs,
    const int* __restrict__ blockmap,
    const float* __restrict__ uwA, const float* __restrict__ uwB,
    float* __restrict__ out)
{
    __shared__ __align__(16) float lx4[128 * 44];   // [c][11 dims][4 nodes]; [9]=1.0 sentinel
    __shared__ float red[2][128][36];               // two reduction slices

    const int tid = threadIdx.x;
    const int z   = tid >> 7;
    const int c   = tid & 127;
    const int c44 = c * 44;

    const int s     = blockmap[2*blockIdx.x];
    const int chunk = blockmap[2*blockIdx.x + 1];
    if (s < 0) return;                             // block-uniform
    const int gbeg = offs[s], gend = offs[s+1];
    const int p0   = gbeg + chunk*NPB;

    int node[4]; bool valid[4];
    #pragma unroll
    for (int q = 0; q < 4; q++) {
        const int pi = p0 + q;
        valid[q] = (pi < gend);
        node[q]  = perm[valid[q] ? pi : p0];
    }

    // Stage 4 nodes' x rows; q compile-time so node[q] stays in registers.
    #pragma unroll
    for (int q = 0; q < 4; q++) {
        const size_t nb = (size_t)node[q] * 1152;
        for (int f = tid; f < 1152; f += 512) {
            const int ch = f / 9, d = f - ch*9;
            lx4[ch*44 + d*4 + q] = x[nb + f];
        }
    }
    { const int ch = tid >> 2, q = tid & 3; lx4[ch*44 + 36 + q] = 1.0f; }
    __syncthreads();

    float acc[4][9];
    #pragma unroll
    for (int q = 0; q < 4; q++)
        #pragma unroll
        for (int i = 0; i < 9; i++) acc[q][i] = 0.f;

    const int mbeg = 55 * z;
    const int mend = (z == 3) ? NMONO : 55 * (z + 1);

    const float* pa = uwA + ((size_t)(s*NMONO + mbeg)*NC + c) * 8;
    const float* pb = uwB +  (size_t)(s*NMONO + mbeg)*NC + c;

    // 2-slot software pipeline: A holds mono m, B holds m+1; prefetch m+2/m+3 (clamped).
    float4 A0 = *(const float4*)pa, A1 = *(const float4*)(pa + 4); float Ab = *pb;
    float4 B0 = *(const float4*)(pa + NC*8), B1 = *(const float4*)(pa + NC*8 + 4); float Bb = *(pb + NC);

    for (int m = mbeg; m < mend; m += 2) {
        const bool h2 = (m + 2 < mend), h3 = (m + 3 < mend);
        const float* ra = h2 ? pa + 2*NC*8 : pa;
        const float* rb = h2 ? pb + 2*NC   : pb;
        const float* sa = h3 ? pa + 3*NC*8 : pa;
        const float* sb = h3 ? pb + 3*NC   : pb;
        const float4 nA0 = *(const float4*)ra, nA1 = *(const float4*)(ra + 4); const float nAb = *rb;
        const float4 nB0 = *(const float4*)sa, nB1 = *(const float4*)(sa + 4); const float nBb = *sb;
        CONSUME(m, A0, A1, Ab)
        if (m + 1 < mend) { CONSUME(m + 1, B0, B1, Bb) }
        A0 = nA0; A1 = nA1; Ab = nAb;
        B0 = nB0; B1 = nB1; Bb = nBb;
        pa += 2*NC*8; pb += 2*NC;
    }

    // Reduce the 4 z-quarters: z2,z3 -> slices; z0,z1 add; z1 -> slice0; z0 adds.
    if (z >= 2) {
        float* r = &red[z-2][c][0];
        #pragma unroll
        for (int q = 0; q < 4; q++)
            #pragma unroll
            for (int i = 0; i < 9; i++) r[q*9 + i] = acc[q][i];
    }
    __syncthreads();
    if (z < 2) {
        const float* r = &red[z][c][0];
        #pragma unroll
        for (int q = 0; q < 4; q++)
            #pragma unroll
            for (int i = 0; i < 9; i++) acc[q][i] += r[q*9 + i];
    }
    __syncthreads();
    if (z == 1) {
        float* r = &red[0][c][0];
        #pragma unroll
        for (int q = 0; q < 4; q++)
            #pragma unroll
            for (int i = 0; i < 9; i++) r[q*9 + i] = acc[q][i];
    }
    __syncthreads();
    if (z == 0) {
        const float* r = &red[0][c][0];
        #pragma unroll
        for (int q = 0; q < 4; q++)
            #pragma unroll
            for (int i = 0; i < 9; i++) acc[q][i] += r[q*9 + i];
        #pragma unroll
        for (int q = 0; q < 4; q++) {
            if (!valid[q]) continue;
            float* orow = out + (size_t)node[q] * 1152;   // [0e: c][1o: 128+c*3+i][2e: 512+c*5+i]
            orow[c] = acc[q][0];
            #pragma unroll
            for (int i = 0; i < 3; i++) orow[128 + c*3 + i] = acc[q][1+i];
            #pragma unroll
            for (int i = 0; i < 5; i++) orow[512 + c*5 + i] = acc[q][4+i];
        }
    }
}

extern "C" void kernel_launch(void* const* d_in, const int* in_sizes, int n_in,
                              void* d_out, int out_size, void* d_ws, size_t ws_size,
                              hipStream_t stream)
{
    const float* x     = (const float*)d_in[0];
    const float* u1_0e = (const float*)d_in[1];
    const float* w1_0e = (const float*)d_in[2];
    const float* u1_1o = (const float*)d_in[3];
    const float* w1_1o = (const float*)d_in[4];
    const float* u1_2e = (const float*)d_in[5];
    const float* w1_2e = (const float*)d_in[6];
    const float* u2_0e = (const float*)d_in[7];
    const float* w2_0e = (const float*)d_in[8];
    const float* u2_1o = (const float*)d_in[9];
    const float* w2_1o = (const float*)d_in[10];
    const float* u2_2e = (const float*)d_in[11];
    const float* w2_2e = (const float*)d_in[12];
    const float* u3_0e = (const float*)d_in[13];
    const float* w3_0e = (const float*)d_in[14];
    const float* u3_1o = (const float*)d_in[15];
    const float* w3_1o = (const float*)d_in[16];
    const float* u3_2e = (const float*)d_in[17];
    const float* w3_2e = (const float*)d_in[18];
    const int*   index = (const int*)d_in[19];
    float* out = (float*)d_out;

    float* uwA     = (float*)d_ws;                        // [S][219][128][8]
    float* uwB     = uwA + (size_t)NS*NMONO*NC*8;         // [S][219][128]
    float* usumAll = uwB + (size_t)NS*NMONO*NC;           // [219][64]
    int*   perm     = (int*)(usumAll + NMONO*64);         // [NN]
    int*   offs     = perm + NN;                          // [NS+1]
    int*   blockmap = offs + (NS+1);                      // [PADBLK*2]

    hipLaunchKernelGGL(build_groups, dim3(1), dim3(NN), 0, stream,
        index, perm, offs, blockmap);

    hipLaunchKernelGGL(u_sym, dim3(NMONO), dim3(64), 0, stream,
        u1_0e, u1_1o, u1_2e, u2_0e, u2_1o, u2_2e, u3_0e, u3_1o, u3_2e, usumAll);

    hipLaunchKernelGGL(uw_fold, dim3(NS*NCHUNKF), dim3(128), 0, stream,
        w1_0e, w1_1o, w1_2e, w2_0e, w2_1o, w2_2e, w3_0e, w3_1o, w3_2e,
        usumAll, uwA, uwB);

    hipLaunchKernelGGL(symcon_main, dim3(PADBLK), dim3(512), 0, stream,
        x, perm, offs, blockmap, uwA, uwB, out);
}